// Round 5
// baseline (2511.365 us; speedup 1.0000x reference)
//
#include <hip/hip_runtime.h>
#include <cstdint>

typedef __bf16 bf16_t;
typedef __bf16 bf16x8 __attribute__((ext_vector_type(8)));
typedef float  f32x4  __attribute__((ext_vector_type(4)));
typedef unsigned int u32;

#define DEPTH 6
#define HEADS 12
#define DH    64
#define DIM   768
#define MLPD  3072
#define FEAT  1000
#define BATCH 32
#define SEQ   197
#define NP    224          // padded j stride for attention matrices
#define TOK   (BATCH*SEQ)  // 6304

__device__ __forceinline__ f32x4 zero4() {
    f32x4 z; z[0] = 0.f; z[1] = 0.f; z[2] = 0.f; z[3] = 0.f; return z;
}

__device__ __forceinline__ f32x4 mfma16(bf16x8 a, bf16x8 b, f32x4 c) {
    return __builtin_amdgcn_mfma_f32_16x16x32_bf16(a, b, c, 0, 0, 0);
}

// async global->LDS, 16B per lane. lds base must be wave-uniform; HW adds lane*16.
typedef const __attribute__((address_space(1))) u32* gas_ptr;
typedef __attribute__((address_space(3))) u32*       las_ptr;
__device__ __forceinline__ void gload16(const bf16_t* g, bf16_t* l) {
    __builtin_amdgcn_global_load_lds((gas_ptr)g, (las_ptr)l, 16, 0, 0);
}

// bijective inverse-XCD chunking (m204): launched L -> logical g so that
// consecutive logical ids sit on the SAME XCD (L2 reuse of shared A-panels).
__device__ __forceinline__ int xcd_logical(int L, int nblk) {
    int q = nblk >> 3, r = nblk & 7, xcd = L & 7;
    return (xcd < r ? xcd * (q + 1) : r * (q + 1) + (xcd - r) * q) + (L >> 3);
}

// ---------------- concat cls + x -> xbuf ----------------
__global__ __launch_bounds__(256) void concat_k(const float* __restrict__ x,
                                                const float* __restrict__ cls,
                                                float* __restrict__ xbuf) {
    int idx = blockIdx.x * 256 + threadIdx.x;      // exactly 6304*768 threads
    int col = idx % DIM;
    int row = idx / DIM;
    int b = row / SEQ, p = row % SEQ;
    xbuf[idx] = (p == 0) ? cls[col] : x[(b * 196 + p - 1) * DIM + col];
}

// ---------------- transpose + fp32->bf16:  W[K][N] -> Wt[N][K] ----------------
__global__ __launch_bounds__(256) void tcvt_k(const float* __restrict__ W,
                                              bf16_t* __restrict__ Wt,
                                              int K, int N) {
    __shared__ float t[32][33];
    int n0 = blockIdx.x * 32, k0 = blockIdx.y * 32;
    int c = threadIdx.x & 31, r = threadIdx.x >> 5;
#pragma unroll
    for (int i = 0; i < 4; i++) {
        int k = k0 + r + i * 8, n = n0 + c;        // K is always a multiple of 32
        t[r + i * 8][c] = (n < N) ? W[k * N + n] : 0.f;
    }
    __syncthreads();
#pragma unroll
    for (int i = 0; i < 4; i++) {
        int n = n0 + r + i * 8, k = k0 + c;
        if (n < N) Wt[n * K + k] = (bf16_t)t[c][r + i * 8];
    }
}

// ---------------- row LayerNorm over 768 cols, fp32 in -> bf16 out ----------------
__global__ __launch_bounds__(256) void ln_k(const float* __restrict__ x, long row_stride,
                                            const float* __restrict__ g,
                                            const float* __restrict__ b,
                                            bf16_t* __restrict__ out) {
    int row = blockIdx.x;
    const float* xr = x + (long)row * row_stride;
    int t = threadIdx.x;
    float v0 = xr[t], v1 = xr[t + 256], v2 = xr[t + 512];
    float s  = v0 + v1 + v2;
    float sq = v0 * v0 + v1 * v1 + v2 * v2;
#pragma unroll
    for (int o = 1; o < 64; o <<= 1) { s += __shfl_xor(s, o); sq += __shfl_xor(sq, o); }
    __shared__ float ss[4], sqs[4];
    int w = t >> 6;
    if ((t & 63) == 0) { ss[w] = s; sqs[w] = sq; }
    __syncthreads();
    s  = ss[0] + ss[1] + ss[2] + ss[3];
    sq = sqs[0] + sqs[1] + sqs[2] + sqs[3];
    float m  = s * (1.f / 768.f);
    float rs = rsqrtf(sq * (1.f / 768.f) - m * m + 1e-5f);
    bf16_t* orow = out + (long)row * DIM;
    orow[t]       = (bf16_t)((v0 - m) * rs * g[t]       + b[t]);
    orow[t + 256] = (bf16_t)((v1 - m) * rs * g[t + 256] + b[t + 256]);
    orow[t + 512] = (bf16_t)((v2 - m) * rs * g[t + 512] + b[t + 512]);
}

// ================= gemmN: 256x256 tile, BK=32, 8 waves (2Mx4N, wave 128x64) =============
// ring-3 LDS (96KB), depth-2 prefetch, counted vmcnt(4), swizzled staging+reads.
// MODE 0: Cb = acc; 2: Cb = gelu(acc + bias)
template <int MODE>
__global__ __launch_bounds__(512, 2) void gemmN_k(const bf16_t* __restrict__ A,
                                                  const bf16_t* __restrict__ Bt,
                                                  const float* __restrict__ bias,
                                                  bf16_t* __restrict__ Cb,
                                                  int M, int N, int K, int nN) {
    __shared__ bf16_t sA[3][256 * 32];   // 48 KB
    __shared__ bf16_t sB[3][256 * 32];   // 48 KB
    int tid = threadIdx.x;
    int g = xcd_logical(blockIdx.x, gridDim.x);
    int bm = (g / nN) * 256, bn = (g % nN) * 256;

    int wave = tid >> 6, lane = tid & 63;
    int wm = (wave >> 2) * 128, wn = (wave & 3) * 64;
    int la = lane & 15, lb = lane >> 4;

    // staging: per tile, A = 2 slabs of 128 rows, B = 2 slabs. 4 gload16/thread/tile.
    int trow = tid >> 2;                       // 0..127
    int sub  = ((tid & 3) ^ (trow & 3)) * 8;   // pre-swizzled source col (elems)
    int rA[2], rB[2];
#pragma unroll
    for (int i = 0; i < 2; i++) {
        int rr = bm + i * 128 + trow; rA[i] = (rr < M) ? rr : M - 1;
        rB[i] = bn + i * 128 + trow;           // bn+255 < N always
    }
    int coff = (lb * 8) ^ ((la & 3) << 3);     // swizzled read col (elems), rows of 32 elems

    f32x4 acc[8][4];
#pragma unroll
    for (int m = 0; m < 8; m++)
#pragma unroll
        for (int n = 0; n < 4; n++) acc[m][n] = zero4();

    int NT = K >> 5;

    auto stageA = [&](int buf, int k0) {
#pragma unroll
        for (int i = 0; i < 2; i++)
            gload16(A + (long)rA[i] * K + k0 + sub, &sA[buf][0] + i * 4096 + wave * 512);
    };
    auto stageB = [&](int buf, int k0) {
#pragma unroll
        for (int i = 0; i < 2; i++)
            gload16(Bt + (long)rB[i] * K + k0 + sub, &sB[buf][0] + i * 4096 + wave * 512);
    };

    // prologue: tiles 0,1 -> bufs 0,1
    stageA(0, 0);  stageB(0, 0);
    stageA(1, 32); stageB(1, 32);

    for (int t = 0; t < NT; t++) {
        int bt = t % 3, bs = (t + 2) % 3;
        int kst = (t + 2) << 5;
        bool st = (t + 2) < NT;
        // tile-t publish: after this, only tile t+1's 4 loads may remain in flight
        if (t + 1 < NT) asm volatile("s_waitcnt vmcnt(4)" ::: "memory");
        else            asm volatile("s_waitcnt vmcnt(0)" ::: "memory");
        __builtin_amdgcn_s_barrier();
        __builtin_amdgcn_sched_barrier(0);

        const bf16_t* cA = &sA[bt][0];
        const bf16_t* cB = &sB[bt][0];
        bf16x8 bv[4];
#pragma unroll
        for (int nf = 0; nf < 4; nf++)
            bv[nf] = *(const bf16x8*)(cB + (wn + nf * 16 + la) * 32 + coff);

        // ---- phase 0: m-half 0 ----
        if (st) stageA(bs, kst);
        bf16x8 av[4];
#pragma unroll
        for (int mf = 0; mf < 4; mf++)
            av[mf] = *(const bf16x8*)(cA + (wm + mf * 16 + la) * 32 + coff);
        asm volatile("s_waitcnt lgkmcnt(0)" ::: "memory");
        __builtin_amdgcn_sched_barrier(0);
        __builtin_amdgcn_s_setprio(1);
#pragma unroll
        for (int mf = 0; mf < 4; mf++)
#pragma unroll
            for (int nf = 0; nf < 4; nf++)
                acc[mf][nf] = mfma16(av[mf], bv[nf], acc[mf][nf]);
        __builtin_amdgcn_s_setprio(0);
        __builtin_amdgcn_sched_barrier(0);

        // ---- phase 1: m-half 1 ----
        if (st) stageB(bs, kst);
#pragma unroll
        for (int mf = 0; mf < 4; mf++)
            av[mf] = *(const bf16x8*)(cA + (wm + 64 + mf * 16 + la) * 32 + coff);
        asm volatile("s_waitcnt lgkmcnt(0)" ::: "memory");
        __builtin_amdgcn_sched_barrier(0);
        __builtin_amdgcn_s_setprio(1);
#pragma unroll
        for (int mf = 0; mf < 4; mf++)
#pragma unroll
            for (int nf = 0; nf < 4; nf++)
                acc[4 + mf][nf] = mfma16(av[mf], bv[nf], acc[4 + mf][nf]);
        __builtin_amdgcn_s_setprio(0);
    }

#pragma unroll
    for (int mi = 0; mi < 8; mi++) {
#pragma unroll
        for (int nf = 0; nf < 4; nf++) {
            int ib = bm + wm + mi * 16 + lb * 4;
            int jb = bn + wn + nf * 16 + la;
            float bvv = (MODE == 0) ? 0.f : bias[jb];
#pragma unroll
            for (int rr = 0; rr < 4; rr++) {
                int i = ib + rr;
                if (i >= M) continue;
                float v = acc[mi][nf][rr];
                if (MODE == 0) {
                    Cb[(long)i * N + jb] = (bf16_t)v;
                } else {
                    float u = v + bvv;
                    Cb[(long)i * N + jb] = (bf16_t)(0.5f * u * (1.f + erff(u * 0.70710678118f)));
                }
            }
        }
    }
}

// ================= gemmS: 128x128 tile, BK=32, 4 waves (2x2, wave 64x64) ================
// ring-3 LDS (48KB -> 3 blocks/CU), depth-2 prefetch, counted vmcnt(4).
// MODE 1: Cf += acc + bias  (residual accumulate)
__global__ __launch_bounds__(256, 4) void gemmS_k(const bf16_t* __restrict__ A,
                                                  const bf16_t* __restrict__ Bt,
                                                  const float* __restrict__ bias,
                                                  float* __restrict__ Cf,
                                                  int M, int N, int K, int nN) {
    __shared__ bf16_t sA[3][128 * 32];   // 24 KB
    __shared__ bf16_t sB[3][128 * 32];   // 24 KB
    int tid = threadIdx.x;
    int g = xcd_logical(blockIdx.x, gridDim.x);
    int bm = (g / nN) * 128, bn = (g % nN) * 128;

    int wave = tid >> 6, lane = tid & 63;
    int wm = (wave >> 1) * 64, wn = (wave & 1) * 64;
    int la = lane & 15, lb = lane >> 4;

    int trow = tid >> 2;                       // 0..63
    int sub  = ((tid & 3) ^ (trow & 3)) * 8;
    int rA[2], rB[2];
#pragma unroll
    for (int i = 0; i < 2; i++) {
        int rr = bm + i * 64 + trow; rA[i] = (rr < M) ? rr : M - 1;
        rB[i] = bn + i * 64 + trow;            // bn+127 < N always
    }
    int coff = (lb * 8) ^ ((la & 3) << 3);

    f32x4 acc[4][4];
#pragma unroll
    for (int m = 0; m < 4; m++)
#pragma unroll
        for (int n = 0; n < 4; n++) acc[m][n] = zero4();

    int NT = K >> 5;

    auto stage = [&](int buf, int k0) {
#pragma unroll
        for (int i = 0; i < 2; i++)
            gload16(A + (long)rA[i] * K + k0 + sub, &sA[buf][0] + i * 2048 + wave * 512);
#pragma unroll
        for (int i = 0; i < 2; i++)
            gload16(Bt + (long)rB[i] * K + k0 + sub, &sB[buf][0] + i * 2048 + wave * 512);
    };

    stage(0, 0);
    stage(1, 32);

    for (int t = 0; t < NT; t++) {
        int bt = t % 3, bs = (t + 2) % 3;
        bool st = (t + 2) < NT;
        if (t + 1 < NT) asm volatile("s_waitcnt vmcnt(4)" ::: "memory");
        else            asm volatile("s_waitcnt vmcnt(0)" ::: "memory");
        __builtin_amdgcn_s_barrier();
        __builtin_amdgcn_sched_barrier(0);

        if (st) stage(bs, (t + 2) << 5);

        const bf16_t* cA = &sA[bt][0];
        const bf16_t* cB = &sB[bt][0];
        bf16x8 av[4], bv[4];
#pragma unroll
        for (int mf = 0; mf < 4; mf++)
            av[mf] = *(const bf16x8*)(cA + (wm + mf * 16 + la) * 32 + coff);
#pragma unroll
        for (int nf = 0; nf < 4; nf++)
            bv[nf] = *(const bf16x8*)(cB + (wn + nf * 16 + la) * 32 + coff);
        asm volatile("s_waitcnt lgkmcnt(0)" ::: "memory");
        __builtin_amdgcn_sched_barrier(0);
        __builtin_amdgcn_s_setprio(1);
#pragma unroll
        for (int mf = 0; mf < 4; mf++)
#pragma unroll
            for (int nf = 0; nf < 4; nf++)
                acc[mf][nf] = mfma16(av[mf], bv[nf], acc[mf][nf]);
        __builtin_amdgcn_s_setprio(0);
    }

#pragma unroll
    for (int mf = 0; mf < 4; mf++) {
#pragma unroll
        for (int nf = 0; nf < 4; nf++) {
            int ib = bm + wm + mf * 16 + lb * 4;
            int jb = bn + wn + nf * 16 + la;
            float bvv = bias[jb];
#pragma unroll
            for (int rr = 0; rr < 4; rr++) {
                int i = ib + rr;
                if (i >= M) continue;
                Cf[(long)i * N + jb] += acc[mf][nf][rr] + bvv;
            }
        }
    }
}

// ---------------- head GEMM: 128x128, 2-phase dbuf (tiny, M=32) ----------------
__global__ __launch_bounds__(256) void gemm_h(const bf16_t* __restrict__ A,
                                              const bf16_t* __restrict__ Bt,
                                              const float* __restrict__ bias,
                                              float* __restrict__ Cf,
                                              int M, int N, int K) {
    __shared__ bf16_t sA[2][128][32];
    __shared__ bf16_t sB[2][128][32];
    int tid = threadIdx.x;
    int bm = blockIdx.x * 128, bn = blockIdx.y * 128;
    int wave = tid >> 6, lane = tid & 63;
    int wm = (wave >> 1) * 64, wn = (wave & 1) * 64;
    int la = lane & 15, lb = lane >> 4;
    int rowA[2], rowB[2], colE[2];
#pragma unroll
    for (int q = 0; q < 2; q++) {
        int li = (wave * 2 + q) * 64 + lane;
        int row = li >> 2;
        colE[q] = (li & 3) * 8;
        int ar = bm + row; if (ar > M - 1) ar = M - 1;
        int br = bn + row; if (br > N - 1) br = N - 1;
        rowA[q] = ar; rowB[q] = br;
    }
    f32x4 acc[4][4];
#pragma unroll
    for (int m = 0; m < 4; m++)
#pragma unroll
        for (int n = 0; n < 4; n++) acc[m][n] = zero4();
    int nt = K >> 5;
#pragma unroll
    for (int q = 0; q < 2; q++) {
        gload16(A  + (long)rowA[q] * K + colE[q], &sA[0][0][0] + (wave * 2 + q) * 512);
        gload16(Bt + (long)rowB[q] * K + colE[q], &sB[0][0][0] + (wave * 2 + q) * 512);
    }
    __syncthreads();
    for (int t = 0; t < nt; t++) {
        int cur = t & 1;
        if (t + 1 < nt) {
            int k0 = (t + 1) << 5;
#pragma unroll
            for (int q = 0; q < 2; q++) {
                gload16(A  + (long)rowA[q] * K + k0 + colE[q], &sA[cur ^ 1][0][0] + (wave * 2 + q) * 512);
                gload16(Bt + (long)rowB[q] * K + k0 + colE[q], &sB[cur ^ 1][0][0] + (wave * 2 + q) * 512);
            }
        }
        bf16x8 af[4], bfr[4];
#pragma unroll
        for (int m = 0; m < 4; m++) af[m]  = *(const bf16x8*)&sA[cur][wm + m * 16 + la][lb * 8];
#pragma unroll
        for (int n = 0; n < 4; n++) bfr[n] = *(const bf16x8*)&sB[cur][wn + n * 16 + la][lb * 8];
#pragma unroll
        for (int m = 0; m < 4; m++)
#pragma unroll
            for (int n = 0; n < 4; n++)
                acc[m][n] = mfma16(af[m], bfr[n], acc[m][n]);
        __syncthreads();
    }
#pragma unroll
    for (int m = 0; m < 4; m++) {
#pragma unroll
        for (int n = 0; n < 4; n++) {
            int ib = bm + wm + m * 16 + lb * 4;
            int jb = bn + wn + n * 16 + la;
            if (jb >= N) continue;
            float bv = bias[jb];
#pragma unroll
            for (int r = 0; r < 4; r++) {
                int i = ib + r;
                if (i >= M) continue;
                Cf[(long)i * N + jb] = acc[m][n][r] + bv;
            }
        }
    }
}

// ---------------- QK^T * scale -> dots (fp32, padded NP) ----------------
__global__ __launch_bounds__(256) void qk_k(const bf16_t* __restrict__ qkv,
                                            float* __restrict__ dots) {
    int bh = blockIdx.z;
    int b = bh / HEADS, h = bh % HEADS;
    int i0 = blockIdx.x * 64, j0 = blockIdx.y * 64;
    __shared__ bf16_t sQ[64][32], sK[64][32];
    int tid = threadIdx.x, wave = tid >> 6, lane = tid & 63;
    int wm = (wave >> 1) * 32, wn = (wave & 1) * 32;
    int la = lane & 15, lb = lane >> 4;
    f32x4 acc[2][2];
#pragma unroll
    for (int m = 0; m < 2; m++)
#pragma unroll
        for (int n = 0; n < 2; n++) acc[m][n] = zero4();

    int row = tid >> 2, col = (tid & 3) * 8;
    int qi = i0 + row; if (qi > SEQ - 1) qi = SEQ - 1;
    int kj = j0 + row; if (kj > SEQ - 1) kj = SEQ - 1;
    const bf16_t* qsrc = qkv + (((b * SEQ + qi) * 3 + 0) * HEADS + h) * DH + col;
    const bf16_t* ksrc = qkv + (((b * SEQ + kj) * 3 + 1) * HEADS + h) * DH + col;

#pragma unroll
    for (int d0 = 0; d0 < 64; d0 += 32) {
        *(bf16x8*)&sQ[row][col] = *(const bf16x8*)(qsrc + d0);
        *(bf16x8*)&sK[row][col] = *(const bf16x8*)(ksrc + d0);
        __syncthreads();
        bf16x8 af[2], bfr[2];
#pragma unroll
        for (int m = 0; m < 2; m++) af[m]  = *(const bf16x8*)&sQ[wm + m * 16 + la][lb * 8];
#pragma unroll
        for (int n = 0; n < 2; n++) bfr[n] = *(const bf16x8*)&sK[wn + n * 16 + la][lb * 8];
#pragma unroll
        for (int m = 0; m < 2; m++)
#pragma unroll
            for (int n = 0; n < 2; n++)
                acc[m][n] = mfma16(af[m], bfr[n], acc[m][n]);
        __syncthreads();
    }
#pragma unroll
    for (int m = 0; m < 2; m++)
#pragma unroll
        for (int n = 0; n < 2; n++)
#pragma unroll
            for (int r = 0; r < 4; r++) {
                int i = i0 + wm + m * 16 + lb * 4 + r;
                int j = j0 + wn + n * 16 + la;
                if (i < SEQ && j < SEQ)
                    dots[((long)bh * SEQ + i) * NP + j] = acc[m][n][r] * 0.125f;
            }
}

// ---------------- fused softmax + re-attention (head mix + LN) -> attn2 (bf16) ----------------
__global__ __launch_bounds__(256) void smre_k(const float* __restrict__ dots,
                                              const float* __restrict__ W,
                                              const float* __restrict__ gg,
                                              const float* __restrict__ bb,
                                              bf16_t* __restrict__ attn2) {
    __shared__ float sm[HEADS][NP];
    __shared__ float sW[HEADS * HEADS];
    __shared__ float sg[HEADS], sb[HEADS];
    int tid = threadIdx.x;
    if (tid < HEADS * HEADS) sW[tid] = W[tid];
    if (tid < HEADS) { sg[tid] = gg[tid]; sb[tid] = bb[tid]; }
    int bi = blockIdx.x;             // b*SEQ + i
    int b = bi / SEQ, i = bi % SEQ;
    int wave = tid >> 6, lane = tid & 63;

    for (int h = wave; h < HEADS; h += 4) {
        const float* p = dots + ((long)(b * HEADS + h) * SEQ + i) * NP;
        float v[4], e[4];
#pragma unroll
        for (int q = 0; q < 4; q++) { int j = lane + 64 * q; v[q] = (j < SEQ) ? p[j] : -3.0e38f; }
        float mx = fmaxf(fmaxf(v[0], v[1]), fmaxf(v[2], v[3]));
#pragma unroll
        for (int o = 1; o < 64; o <<= 1) mx = fmaxf(mx, __shfl_xor(mx, o));
        float s = 0.f;
#pragma unroll
        for (int q = 0; q < 4; q++) {
            int j = lane + 64 * q;
            e[q] = (j < SEQ) ? __expf(v[q] - mx) : 0.f;
            s += e[q];
        }
#pragma unroll
        for (int o = 1; o < 64; o <<= 1) s += __shfl_xor(s, o);
        float inv = 1.f / s;
#pragma unroll
        for (int q = 0; q < 4; q++) { int j = lane + 64 * q; if (j < NP) sm[h][j] = e[q] * inv; }
    }
    __syncthreads();

    int j = tid;
    if (j >= NP) return;
    bool valid = j < SEQ;
    float vals[HEADS];
#pragma unroll
    for (int h = 0; h < HEADS; h++) vals[h] = valid ? sm[h][j] : 0.f;
    float mix[HEADS];
    float s = 0.f, sq = 0.f;
#pragma unroll
    for (int g = 0; g < HEADS; g++) {
        float a = 0.f;
#pragma unroll
        for (int h = 0; h < HEADS; h++) a += vals[h] * sW[h * HEADS + g];
        mix[g] = a; s += a; sq += a * a;
    }
    float m  = s * (1.f / 12.f);
    float rs = rsqrtf(sq * (1.f / 12.f) - m * m + 1e-5f);
    long base = ((long)(b * HEADS) * SEQ + i) * NP + j;
    const long hs = (long)SEQ * NP;
#pragma unroll
    for (int g = 0; g < HEADS; g++) {
        float o = valid ? ((mix[g] - m) * rs * sg[g] + sb[g]) : 0.f;
        attn2[base + g * hs] = (bf16_t)o;
    }
}

// ---------------- PV: out[b,h,i,d] = sum_j attn2 * v  -> aout[b,i,h*64+d] (bf16) ----------------
__global__ __launch_bounds__(256) void pv_k(const bf16_t* __restrict__ attn2,
                                            const bf16_t* __restrict__ qkv,
                                            bf16_t* __restrict__ aout) {
    int bh = blockIdx.y;
    int b = bh / HEADS, h = bh % HEADS;
    int i0 = blockIdx.x * 64;
    __shared__ bf16_t sP[64][32];
    __shared__ bf16_t sVt[64][32];   // logical [d][j], XOR-swizzled on j-blocks
    int tid = threadIdx.x, wave = tid >> 6, lane = tid & 63;
    int wm = (wave >> 1) * 32, wn = (wave & 1) * 32;
    int la = lane & 15, lb = lane >> 4;
    f32x4 acc[2][2];
#pragma unroll
    for (int m = 0; m < 2; m++)
#pragma unroll
        for (int n = 0; n < 2; n++) acc[m][n] = zero4();

    int prow = tid >> 2, pcol = (tid & 3) * 8;
    int pi = i0 + prow; if (pi > SEQ - 1) pi = SEQ - 1;
    const bf16_t* psrc = attn2 + ((long)bh * SEQ + pi) * NP + pcol;
    int jl = tid >> 3, dblk = (tid & 7) * 8;
    int jlx = jl ^ ((tid & 3) << 3);

    for (int j0 = 0; j0 < NP; j0 += 32) {
        *(bf16x8*)&sP[prow][pcol] = *(const bf16x8*)(psrc + j0);
        int jg = j0 + jl;
        bf16x8 vv;
#pragma unroll
        for (int e = 0; e < 8; e++) vv[e] = (bf16_t)0.f;
        if (jg < SEQ)
            vv = *(const bf16x8*)(qkv + (((b * SEQ + jg) * 3 + 2) * HEADS + h) * DH + dblk);
#pragma unroll
        for (int e = 0; e < 8; e++) sVt[dblk + e][jlx] = vv[e];
        __syncthreads();
        bf16x8 af[2], bfr[2];
#pragma unroll
        for (int m = 0; m < 2; m++) af[m] = *(const bf16x8*)&sP[wm + m * 16 + la][lb * 8];
#pragma unroll
        for (int n = 0; n < 2; n++) {
            int rowd = wn + n * 16 + la;
            int colj = (lb * 8) ^ (((rowd >> 3) & 3) << 3);
            bfr[n] = *(const bf16x8*)&sVt[rowd][colj];
        }
#pragma unroll
        for (int m = 0; m < 2; m++)
#pragma unroll
            for (int n = 0; n < 2; n++)
                acc[m][n] = mfma16(af[m], bfr[n], acc[m][n]);
        __syncthreads();
    }
#pragma unroll
    for (int m = 0; m < 2; m++)
#pragma unroll
        for (int n = 0; n < 2; n++)
#pragma unroll
            for (int r = 0; r < 4; r++) {
                int i = i0 + wm + m * 16 + lb * 4 + r;
                int d = wn + n * 16 + la;
                if (i < SEQ)
                    aout[((long)b * SEQ + i) * DIM + h * DH + d] = (bf16_t)acc[m][n][r];
            }
}

// ---------------- host orchestration ----------------
extern "C" void kernel_launch(void* const* d_in, const int* in_sizes, int n_in,
                              void* d_out, int out_size, void* d_ws, size_t ws_size,
                              hipStream_t stream) {
    const float* x        = (const float*)d_in[0];
    const float* cls      = (const float*)d_in[1];
    const float* ln1_g    = (const float*)d_in[2];
    const float* ln1_b    = (const float*)d_in[3];
    const float* w_qkv    = (const float*)d_in[4];
    const float* reattn_w = (const float*)d_in[5];
    const float* reattn_g = (const float*)d_in[6];
    const float* reattn_b = (const float*)d_in[7];
    const float* w_out    = (const float*)d_in[8];
    const float* b_out    = (const float*)d_in[9];
    const float* ln2_g    = (const float*)d_in[10];
    const float* ln2_b    = (const float*)d_in[11];
    const float* w1       = (const float*)d_in[12];
    const float* b1       = (const float*)d_in[13];
    const float* w2       = (const float*)d_in[14];
    const float* b2       = (const float*)d_in[15];
    const float* lnf_g    = (const float*)d_in[16];
    const float* lnf_b    = (const float*)d_in[17];
    const float* w_head   = (const float*)d_in[18];
    const float* b_head   = (const float*)d_in[19];
    float* out = (float*)d_out;

    char* p = (char*)d_ws;
    auto alloc = [&](size_t bytes) -> char* {
        char* r = p;
        p += (bytes + 255) & ~(size_t)255;
        return r;
    };
    bf16_t* wt      = (bf16_t*)alloc(2ULL * MLPD * DIM);
    bf16_t* wt_head = (bf16_t*)alloc(2ULL * FEAT * DIM);
    float*  xbuf    = (float*)alloc(4ULL * TOK * DIM);
    bf16_t* h_ln    = (bf16_t*)alloc(2ULL * TOK * DIM);
    bf16_t* qkv     = (bf16_t*)alloc(2ULL * TOK * 3 * DIM);
    float*  dots    = (float*)alloc(4ULL * BATCH * HEADS * SEQ * NP);
    bf16_t* h_mid   = (bf16_t*)dots;                               // lifetime-overlaid with dots
    bf16_t* attn2   = (bf16_t*)alloc(2ULL * BATCH * HEADS * SEQ * NP);
    bf16_t* aout    = (bf16_t*)alloc(2ULL * TOK * DIM);

    dim3 B256(256), B512(512);
    const int NM256 = (TOK + 255) / 256;   // 25
    const int NM128 = (TOK + 127) / 128;   // 50
    concat_k<<<(TOK * DIM) / 256, B256, 0, stream>>>(x, cls, xbuf);
    tcvt_k<<<dim3((FEAT + 31) / 32, DIM / 32), B256, 0, stream>>>(w_head, wt_head, DIM, FEAT);

    for (int l = 0; l < DEPTH; l++) {
        ln_k<<<TOK, B256, 0, stream>>>(xbuf, DIM, ln1_g + l * DIM, ln1_b + l * DIM, h_ln);
        tcvt_k<<<dim3(2304 / 32, DIM / 32), B256, 0, stream>>>(w_qkv + (long)l * DIM * 2304, wt, DIM, 2304);
        gemmN_k<0><<<NM256 * 9, B512, 0, stream>>>(h_ln, wt, nullptr, qkv, TOK, 2304, DIM, 9);
        qk_k<<<dim3(4, 4, BATCH * HEADS), B256, 0, stream>>>(qkv, dots);
        smre_k<<<TOK, B256, 0, stream>>>(
            dots, reattn_w + l * HEADS * HEADS, reattn_g + l * HEADS, reattn_b + l * HEADS, attn2);
        pv_k<<<dim3(4, BATCH * HEADS), B256, 0, stream>>>(attn2, qkv, aout);
        tcvt_k<<<dim3(DIM / 32, DIM / 32), B256, 0, stream>>>(w_out + (long)l * DIM * DIM, wt, DIM, DIM);
        gemmS_k<<<NM128 * 6, B256, 0, stream>>>(aout, wt, b_out + l * DIM, xbuf, TOK, DIM, DIM, 6);
        ln_k<<<TOK, B256, 0, stream>>>(xbuf, DIM, ln2_g + l * DIM, ln2_b + l * DIM, h_ln);
        tcvt_k<<<dim3(MLPD / 32, DIM / 32), B256, 0, stream>>>(w1 + (long)l * DIM * MLPD, wt, DIM, MLPD);
        gemmN_k<2><<<NM256 * 12, B512, 0, stream>>>(h_ln, wt, b1 + l * MLPD, h_mid, TOK, MLPD, DIM, 12);
        tcvt_k<<<dim3(DIM / 32, MLPD / 32), B256, 0, stream>>>(w2 + (long)l * MLPD * DIM, wt, MLPD, DIM);
        gemmS_k<<<NM128 * 6, B256, 0, stream>>>(h_mid, wt, b2 + l * DIM, xbuf, TOK, DIM, MLPD, 6);
    }

    ln_k<<<BATCH, B256, 0, stream>>>(xbuf, (long)SEQ * DIM, lnf_g, lnf_b, h_ln);
    gemm_h<<<dim3(1, 8), B256, 0, stream>>>(h_ln, wt_head, b_head, out, BATCH, FEAT, DIM);
}

// Round 6
// 2067.980 us; speedup vs baseline: 1.2144x; 1.2144x over previous
//
#include <hip/hip_runtime.h>
#include <cstdint>

typedef __bf16 bf16_t;
typedef __bf16 bf16x8 __attribute__((ext_vector_type(8)));
typedef float  f32x4  __attribute__((ext_vector_type(4)));
typedef unsigned int u32;

#define DEPTH 6
#define HEADS 12
#define DH    64
#define DIM   768
#define MLPD  3072
#define FEAT  1000
#define BATCH 32
#define SEQ   197
#define NP    224          // padded j stride for attention matrices
#define TOK   (BATCH*SEQ)  // 6304

__device__ __forceinline__ f32x4 zero4() {
    f32x4 z; z[0] = 0.f; z[1] = 0.f; z[2] = 0.f; z[3] = 0.f; return z;
}

__device__ __forceinline__ f32x4 mfma16(bf16x8 a, bf16x8 b, f32x4 c) {
    return __builtin_amdgcn_mfma_f32_16x16x32_bf16(a, b, c, 0, 0, 0);
}

// async global->LDS, 16B per lane. lds base must be wave-uniform; HW adds lane*16.
typedef const __attribute__((address_space(1))) u32* gas_ptr;
typedef __attribute__((address_space(3))) u32*       las_ptr;
__device__ __forceinline__ void gload16(const bf16_t* g, bf16_t* l) {
    __builtin_amdgcn_global_load_lds((gas_ptr)g, (las_ptr)l, 16, 0, 0);
}

// bijective inverse-XCD chunking (m204): consecutive logical ids share an XCD L2.
__device__ __forceinline__ int xcd_logical(int L, int nblk) {
    int q = nblk >> 3, r = nblk & 7, xcd = L & 7;
    return (xcd < r ? xcd * (q + 1) : r * (q + 1) + (xcd - r) * q) + (L >> 3);
}

// ---------------- concat cls + x -> xbuf ----------------
__global__ __launch_bounds__(256) void concat_k(const float* __restrict__ x,
                                                const float* __restrict__ cls,
                                                float* __restrict__ xbuf) {
    int idx = blockIdx.x * 256 + threadIdx.x;      // exactly 6304*768 threads
    int col = idx % DIM;
    int row = idx / DIM;
    int b = row / SEQ, p = row % SEQ;
    xbuf[idx] = (p == 0) ? cls[col] : x[(b * 196 + p - 1) * DIM + col];
}

// ---------------- transpose + fp32->bf16:  W[K][N] -> Wt[N][K] ----------------
__global__ __launch_bounds__(256) void tcvt_k(const float* __restrict__ W,
                                              bf16_t* __restrict__ Wt,
                                              int K, int N) {
    __shared__ float t[32][33];
    int n0 = blockIdx.x * 32, k0 = blockIdx.y * 32;
    int c = threadIdx.x & 31, r = threadIdx.x >> 5;
#pragma unroll
    for (int i = 0; i < 4; i++) {
        int k = k0 + r + i * 8, n = n0 + c;        // K is always a multiple of 32
        t[r + i * 8][c] = (n < N) ? W[k * N + n] : 0.f;
    }
    __syncthreads();
#pragma unroll
    for (int i = 0; i < 4; i++) {
        int n = n0 + r + i * 8, k = k0 + c;
        if (n < N) Wt[n * K + k] = (bf16_t)t[c][r + i * 8];
    }
}

// ---------------- row LayerNorm over 768 cols, fp32 in -> bf16 out ----------------
__global__ __launch_bounds__(256) void ln_k(const float* __restrict__ x, long row_stride,
                                            const float* __restrict__ g,
                                            const float* __restrict__ b,
                                            bf16_t* __restrict__ out) {
    int row = blockIdx.x;
    const float* xr = x + (long)row * row_stride;
    int t = threadIdx.x;
    float v0 = xr[t], v1 = xr[t + 256], v2 = xr[t + 512];
    float s  = v0 + v1 + v2;
    float sq = v0 * v0 + v1 * v1 + v2 * v2;
#pragma unroll
    for (int o = 1; o < 64; o <<= 1) { s += __shfl_xor(s, o); sq += __shfl_xor(sq, o); }
    __shared__ float ss[4], sqs[4];
    int w = t >> 6;
    if ((t & 63) == 0) { ss[w] = s; sqs[w] = sq; }
    __syncthreads();
    s  = ss[0] + ss[1] + ss[2] + ss[3];
    sq = sqs[0] + sqs[1] + sqs[2] + sqs[3];
    float m  = s * (1.f / 768.f);
    float rs = rsqrtf(sq * (1.f / 768.f) - m * m + 1e-5f);
    bf16_t* orow = out + (long)row * DIM;
    orow[t]       = (bf16_t)((v0 - m) * rs * g[t]       + b[t]);
    orow[t + 256] = (bf16_t)((v1 - m) * rs * g[t + 256] + b[t + 256]);
    orow[t + 512] = (bf16_t)((v2 - m) * rs * g[t + 512] + b[t + 512]);
}

// ================= big GEMM: 128x128, BK=32, 4 waves, ring-3 counted-vmcnt ==============
// Ledger: prologue stages tiles 0,1. Entering tile t: outstanding = tile t (4 loads) +
// tile t+1 (4). vmcnt(4) retires tile t's; barrier publishes across waves; stage of tile
// t+2 overwrites buf holding tile t-1 (consumed before this barrier). Last tile: vmcnt(0).
// LDS XOR swizzle: 16B-granule g at row r holds global granule g ^ ((r>>1)&3) -> all
// fragment ds_read_b128 are 2-way (free). Staged via pre-swizzled global source.
// MODE 0: Cb = acc; 1: Cf += acc + bias; 2: Cb = gelu(acc + bias)
template <int MODE>
__global__ __launch_bounds__(256, 3) void gemm_k(const bf16_t* __restrict__ A,
                                                 const bf16_t* __restrict__ Bt,
                                                 const float* __restrict__ bias,
                                                 float* __restrict__ Cf,
                                                 bf16_t* __restrict__ Cb,
                                                 int M, int N, int K, int nN) {
    __shared__ bf16_t sA[3][128 * 32];   // 24 KB
    __shared__ bf16_t sB[3][128 * 32];   // 24 KB
    bf16_t* sa = &sA[0][0];
    bf16_t* sb = &sB[0][0];
    int tid = threadIdx.x;
    int g = xcd_logical(blockIdx.x, gridDim.x);
    int bm = (g / nN) * 128, bn = (g % nN) * 128;
    int wave = tid >> 6, lane = tid & 63;
    int wm = (wave >> 1) * 64, wn = (wave & 1) * 64;
    int la = lane & 15, lb = lane >> 4;

    // staging: 4 issues of 4KB (256 thr x 16B); issue covers 64 rows x 64B.
    int tq = tid >> 2;                                   // row within issue
    int scol = ((tid & 3) ^ ((tid >> 3) & 3)) * 8;       // pre-swizzled source col (elems)
    int a0 = bm + tq;      if (a0 > M - 1) a0 = M - 1;
    int a1 = bm + 64 + tq; if (a1 > M - 1) a1 = M - 1;
    int b0 = bn + tq, b1 = bn + 64 + tq;                 // N exact multiple of 128
    int wslot = wave * 512;                              // elems; lane adds l*8 in HW

    // swizzled fragment read granule
    int lbx = (lb ^ ((la >> 1) & 3)) << 3;               // elems

    f32x4 acc[4][4];
#pragma unroll
    for (int m = 0; m < 4; m++)
#pragma unroll
        for (int n = 0; n < 4; n++) acc[m][n] = zero4();

    int NT = K >> 5;

    auto stage = [&](int buf, int kt) {
        int k0 = kt << 5;
        gload16(A  + (long)a0 * K + k0 + scol, sa + buf * 4096 + wslot);
        gload16(A  + (long)a1 * K + k0 + scol, sa + buf * 4096 + 2048 + wslot);
        gload16(Bt + (long)b0 * K + k0 + scol, sb + buf * 4096 + wslot);
        gload16(Bt + (long)b1 * K + k0 + scol, sb + buf * 4096 + 2048 + wslot);
    };

    stage(0, 0);
    stage(1, 1);

    for (int t = 0; t < NT; t++) {
        if (t < NT - 1) asm volatile("s_waitcnt vmcnt(4)" ::: "memory");
        else            asm volatile("s_waitcnt vmcnt(0)" ::: "memory");
        __builtin_amdgcn_s_barrier();
        asm volatile("" ::: "memory");

        if (t + 2 < NT) stage((t + 2) % 3, t + 2);

        const bf16_t* cA = sa + (t % 3) * 4096;
        const bf16_t* cB = sb + (t % 3) * 4096;
        bf16x8 av[4], bv[4];
#pragma unroll
        for (int mf = 0; mf < 4; mf++)
            av[mf] = *(const bf16x8*)(cA + (wm + mf * 16 + la) * 32 + lbx);
#pragma unroll
        for (int nf = 0; nf < 4; nf++)
            bv[nf] = *(const bf16x8*)(cB + (wn + nf * 16 + la) * 32 + lbx);
        __builtin_amdgcn_s_setprio(1);
#pragma unroll
        for (int mf = 0; mf < 4; mf++)
#pragma unroll
            for (int nf = 0; nf < 4; nf++)
                acc[mf][nf] = mfma16(av[mf], bv[nf], acc[mf][nf]);
        __builtin_amdgcn_s_setprio(0);
    }

#pragma unroll
    for (int mf = 0; mf < 4; mf++) {
#pragma unroll
        for (int nf = 0; nf < 4; nf++) {
            int ib = bm + wm + mf * 16 + lb * 4;
            int jb = bn + wn + nf * 16 + la;
            float bvv = (MODE == 0) ? 0.f : bias[jb];
#pragma unroll
            for (int rr = 0; rr < 4; rr++) {
                int i = ib + rr;
                if (i >= M) continue;
                float v = acc[mf][nf][rr];
                if (MODE == 0) {
                    Cb[(long)i * N + jb] = (bf16_t)v;
                } else if (MODE == 1) {
                    Cf[(long)i * N + jb] += v + bvv;
                } else {
                    float u = v + bvv;
                    Cb[(long)i * N + jb] = (bf16_t)(0.5f * u * (1.f + erff(u * 0.70710678118f)));
                }
            }
        }
    }
}

// ---------------- head GEMM: 128x128, 2-phase dbuf (tiny, M=32) ----------------
__global__ __launch_bounds__(256) void gemm_h(const bf16_t* __restrict__ A,
                                              const bf16_t* __restrict__ Bt,
                                              const float* __restrict__ bias,
                                              float* __restrict__ Cf,
                                              int M, int N, int K) {
    __shared__ bf16_t sA[2][128][32];
    __shared__ bf16_t sB[2][128][32];
    int tid = threadIdx.x;
    int bm = blockIdx.x * 128, bn = blockIdx.y * 128;
    int wave = tid >> 6, lane = tid & 63;
    int wm = (wave >> 1) * 64, wn = (wave & 1) * 64;
    int la = lane & 15, lb = lane >> 4;
    int rowA[2], rowB[2], colE[2];
#pragma unroll
    for (int q = 0; q < 2; q++) {
        int li = (wave * 2 + q) * 64 + lane;
        int row = li >> 2;
        colE[q] = (li & 3) * 8;
        int ar = bm + row; if (ar > M - 1) ar = M - 1;
        int br = bn + row; if (br > N - 1) br = N - 1;
        rowA[q] = ar; rowB[q] = br;
    }
    f32x4 acc[4][4];
#pragma unroll
    for (int m = 0; m < 4; m++)
#pragma unroll
        for (int n = 0; n < 4; n++) acc[m][n] = zero4();
    int nt = K >> 5;
#pragma unroll
    for (int q = 0; q < 2; q++) {
        gload16(A  + (long)rowA[q] * K + colE[q], &sA[0][0][0] + (wave * 2 + q) * 512);
        gload16(Bt + (long)rowB[q] * K + colE[q], &sB[0][0][0] + (wave * 2 + q) * 512);
    }
    __syncthreads();
    for (int t = 0; t < nt; t++) {
        int cur = t & 1;
        if (t + 1 < nt) {
            int k0 = (t + 1) << 5;
#pragma unroll
            for (int q = 0; q < 2; q++) {
                gload16(A  + (long)rowA[q] * K + k0 + colE[q], &sA[cur ^ 1][0][0] + (wave * 2 + q) * 512);
                gload16(Bt + (long)rowB[q] * K + k0 + colE[q], &sB[cur ^ 1][0][0] + (wave * 2 + q) * 512);
            }
        }
        bf16x8 af[4], bfr[4];
#pragma unroll
        for (int m = 0; m < 4; m++) af[m]  = *(const bf16x8*)&sA[cur][wm + m * 16 + la][lb * 8];
#pragma unroll
        for (int n = 0; n < 4; n++) bfr[n] = *(const bf16x8*)&sB[cur][wn + n * 16 + la][lb * 8];
#pragma unroll
        for (int m = 0; m < 4; m++)
#pragma unroll
            for (int n = 0; n < 4; n++)
                acc[m][n] = mfma16(af[m], bfr[n], acc[m][n]);
        __syncthreads();
    }
#pragma unroll
    for (int m = 0; m < 4; m++) {
#pragma unroll
        for (int n = 0; n < 4; n++) {
            int ib = bm + wm + m * 16 + lb * 4;
            int jb = bn + wn + n * 16 + la;
            if (jb >= N) continue;
            float bv = bias[jb];
#pragma unroll
            for (int r = 0; r < 4; r++) {
                int i = ib + r;
                if (i >= M) continue;
                Cf[(long)i * N + jb] = acc[m][n][r] + bv;
            }
        }
    }
}

// ---------------- QK^T * scale -> dots (fp32, padded NP) ----------------
__global__ __launch_bounds__(256) void qk_k(const bf16_t* __restrict__ qkv,
                                            float* __restrict__ dots) {
    int bh = blockIdx.z;
    int b = bh / HEADS, h = bh % HEADS;
    int i0 = blockIdx.x * 64, j0 = blockIdx.y * 64;
    __shared__ bf16_t sQ[64][32], sK[64][32];
    int tid = threadIdx.x, wave = tid >> 6, lane = tid & 63;
    int wm = (wave >> 1) * 32, wn = (wave & 1) * 32;
    int la = lane & 15, lb = lane >> 4;
    f32x4 acc[2][2];
#pragma unroll
    for (int m = 0; m < 2; m++)
#pragma unroll
        for (int n = 0; n < 2; n++) acc[m][n] = zero4();

    int row = tid >> 2, col = (tid & 3) * 8;
    int qi = i0 + row; if (qi > SEQ - 1) qi = SEQ - 1;
    int kj = j0 + row; if (kj > SEQ - 1) kj = SEQ - 1;
    const bf16_t* qsrc = qkv + (((b * SEQ + qi) * 3 + 0) * HEADS + h) * DH + col;
    const bf16_t* ksrc = qkv + (((b * SEQ + kj) * 3 + 1) * HEADS + h) * DH + col;

#pragma unroll
    for (int d0 = 0; d0 < 64; d0 += 32) {
        *(bf16x8*)&sQ[row][col] = *(const bf16x8*)(qsrc + d0);
        *(bf16x8*)&sK[row][col] = *(const bf16x8*)(ksrc + d0);
        __syncthreads();
        bf16x8 af[2], bfr[2];
#pragma unroll
        for (int m = 0; m < 2; m++) af[m]  = *(const bf16x8*)&sQ[wm + m * 16 + la][lb * 8];
#pragma unroll
        for (int n = 0; n < 2; n++) bfr[n] = *(const bf16x8*)&sK[wn + n * 16 + la][lb * 8];
#pragma unroll
        for (int m = 0; m < 2; m++)
#pragma unroll
            for (int n = 0; n < 2; n++)
                acc[m][n] = mfma16(af[m], bfr[n], acc[m][n]);
        __syncthreads();
    }
#pragma unroll
    for (int m = 0; m < 2; m++)
#pragma unroll
        for (int n = 0; n < 2; n++)
#pragma unroll
            for (int r = 0; r < 4; r++) {
                int i = i0 + wm + m * 16 + lb * 4 + r;
                int j = j0 + wn + n * 16 + la;
                if (i < SEQ && j < SEQ)
                    dots[((long)bh * SEQ + i) * NP + j] = acc[m][n][r] * 0.125f;
            }
}

// ---------------- fused softmax + re-attention (head mix + LN) -> attn2 (bf16) ----------------
__global__ __launch_bounds__(256) void smre_k(const float* __restrict__ dots,
                                              const float* __restrict__ W,
                                              const float* __restrict__ gg,
                                              const float* __restrict__ bb,
                                              bf16_t* __restrict__ attn2) {
    __shared__ float sm[HEADS][NP];
    __shared__ float sW[HEADS * HEADS];
    __shared__ float sg[HEADS], sb[HEADS];
    int tid = threadIdx.x;
    if (tid < HEADS * HEADS) sW[tid] = W[tid];
    if (tid < HEADS) { sg[tid] = gg[tid]; sb[tid] = bb[tid]; }
    int bi = blockIdx.x;             // b*SEQ + i
    int b = bi / SEQ, i = bi % SEQ;
    int wave = tid >> 6, lane = tid & 63;

    for (int h = wave; h < HEADS; h += 4) {
        const float* p = dots + ((long)(b * HEADS + h) * SEQ + i) * NP;
        float v[4], e[4];
#pragma unroll
        for (int q = 0; q < 4; q++) { int j = lane + 64 * q; v[q] = (j < SEQ) ? p[j] : -3.0e38f; }
        float mx = fmaxf(fmaxf(v[0], v[1]), fmaxf(v[2], v[3]));
#pragma unroll
        for (int o = 1; o < 64; o <<= 1) mx = fmaxf(mx, __shfl_xor(mx, o));
        float s = 0.f;
#pragma unroll
        for (int q = 0; q < 4; q++) {
            int j = lane + 64 * q;
            e[q] = (j < SEQ) ? __expf(v[q] - mx) : 0.f;
            s += e[q];
        }
#pragma unroll
        for (int o = 1; o < 64; o <<= 1) s += __shfl_xor(s, o);
        float inv = 1.f / s;
#pragma unroll
        for (int q = 0; q < 4; q++) { int j = lane + 64 * q; if (j < NP) sm[h][j] = e[q] * inv; }
    }
    __syncthreads();

    int j = tid;
    if (j >= NP) return;
    bool valid = j < SEQ;
    float vals[HEADS];
#pragma unroll
    for (int h = 0; h < HEADS; h++) vals[h] = valid ? sm[h][j] : 0.f;
    float mix[HEADS];
    float s = 0.f, sq = 0.f;
#pragma unroll
    for (int g = 0; g < HEADS; g++) {
        float a = 0.f;
#pragma unroll
        for (int h = 0; h < HEADS; h++) a += vals[h] * sW[h * HEADS + g];
        mix[g] = a; s += a; sq += a * a;
    }
    float m  = s * (1.f / 12.f);
    float rs = rsqrtf(sq * (1.f / 12.f) - m * m + 1e-5f);
    long base = ((long)(b * HEADS) * SEQ + i) * NP + j;
    const long hs = (long)SEQ * NP;
#pragma unroll
    for (int g = 0; g < HEADS; g++) {
        float o = valid ? ((mix[g] - m) * rs * sg[g] + sb[g]) : 0.f;
        attn2[base + g * hs] = (bf16_t)o;
    }
}

// ---------------- PV: out[b,h,i,d] = sum_j attn2 * v  -> aout[b,i,h*64+d] (bf16) ----------------
__global__ __launch_bounds__(256) void pv_k(const bf16_t* __restrict__ attn2,
                                            const bf16_t* __restrict__ qkv,
                                            bf16_t* __restrict__ aout) {
    int bh = blockIdx.y;
    int b = bh / HEADS, h = bh % HEADS;
    int i0 = blockIdx.x * 64;
    __shared__ bf16_t sP[64][32];
    __shared__ bf16_t sVt[64][32];   // logical [d][j], XOR-swizzled on j-blocks
    int tid = threadIdx.x, wave = tid >> 6, lane = tid & 63;
    int wm = (wave >> 1) * 32, wn = (wave & 1) * 32;
    int la = lane & 15, lb = lane >> 4;
    f32x4 acc[2][2];
#pragma unroll
    for (int m = 0; m < 2; m++)
#pragma unroll
        for (int n = 0; n < 2; n++) acc[m][n] = zero4();

    int prow = tid >> 2, pcol = (tid & 3) * 8;
    int pi = i0 + prow; if (pi > SEQ - 1) pi = SEQ - 1;
    const bf16_t* psrc = attn2 + ((long)bh * SEQ + pi) * NP + pcol;
    int jl = tid >> 3, dblk = (tid & 7) * 8;
    int jlx = jl ^ ((tid & 3) << 3);

    for (int j0 = 0; j0 < NP; j0 += 32) {
        *(bf16x8*)&sP[prow][pcol] = *(const bf16x8*)(psrc + j0);
        int jg = j0 + jl;
        bf16x8 vv;
#pragma unroll
        for (int e = 0; e < 8; e++) vv[e] = (bf16_t)0.f;
        if (jg < SEQ)
            vv = *(const bf16x8*)(qkv + (((b * SEQ + jg) * 3 + 2) * HEADS + h) * DH + dblk);
#pragma unroll
        for (int e = 0; e < 8; e++) sVt[dblk + e][jlx] = vv[e];
        __syncthreads();
        bf16x8 af[2], bfr[2];
#pragma unroll
        for (int m = 0; m < 2; m++) af[m] = *(const bf16x8*)&sP[wm + m * 16 + la][lb * 8];
#pragma unroll
        for (int n = 0; n < 2; n++) {
            int rowd = wn + n * 16 + la;
            int colj = (lb * 8) ^ (((rowd >> 3) & 3) << 3);
            bfr[n] = *(const bf16x8*)&sVt[rowd][colj];
        }
#pragma unroll
        for (int m = 0; m < 2; m++)
#pragma unroll
            for (int n = 0; n < 2; n++)
                acc[m][n] = mfma16(af[m], bfr[n], acc[m][n]);
        __syncthreads();
    }
#pragma unroll
    for (int m = 0; m < 2; m++)
#pragma unroll
        for (int n = 0; n < 2; n++)
#pragma unroll
            for (int r = 0; r < 4; r++) {
                int i = i0 + wm + m * 16 + lb * 4 + r;
                int d = wn + n * 16 + la;
                if (i < SEQ)
                    aout[((long)b * SEQ + i) * DIM + h * DH + d] = (bf16_t)acc[m][n][r];
            }
}

// ---------------- host orchestration ----------------
extern "C" void kernel_launch(void* const* d_in, const int* in_sizes, int n_in,
                              void* d_out, int out_size, void* d_ws, size_t ws_size,
                              hipStream_t stream) {
    const float* x        = (const float*)d_in[0];
    const float* cls      = (const float*)d_in[1];
    const float* ln1_g    = (const float*)d_in[2];
    const float* ln1_b    = (const float*)d_in[3];
    const float* w_qkv    = (const float*)d_in[4];
    const float* reattn_w = (const float*)d_in[5];
    const float* reattn_g = (const float*)d_in[6];
    const float* reattn_b = (const float*)d_in[7];
    const float* w_out    = (const float*)d_in[8];
    const float* b_out    = (const float*)d_in[9];
    const float* ln2_g    = (const float*)d_in[10];
    const float* ln2_b    = (const float*)d_in[11];
    const float* w1       = (const float*)d_in[12];
    const float* b1       = (const float*)d_in[13];
    const float* w2       = (const float*)d_in[14];
    const float* b2       = (const float*)d_in[15];
    const float* lnf_g    = (const float*)d_in[16];
    const float* lnf_b    = (const float*)d_in[17];
    const float* w_head   = (const float*)d_in[18];
    const float* b_head   = (const float*)d_in[19];
    float* out = (float*)d_out;

    char* p = (char*)d_ws;
    auto alloc = [&](size_t bytes) -> char* {
        char* r = p;
        p += (bytes + 255) & ~(size_t)255;
        return r;
    };
    bf16_t* wt      = (bf16_t*)alloc(2ULL * MLPD * DIM);
    bf16_t* wt_head = (bf16_t*)alloc(2ULL * FEAT * DIM);
    float*  xbuf    = (float*)alloc(4ULL * TOK * DIM);
    bf16_t* h_ln    = (bf16_t*)alloc(2ULL * TOK * DIM);
    bf16_t* qkv     = (bf16_t*)alloc(2ULL * TOK * 3 * DIM);
    float*  dots    = (float*)alloc(4ULL * BATCH * HEADS * SEQ * NP);
    bf16_t* h_mid   = (bf16_t*)dots;                               // lifetime-overlaid with dots
    bf16_t* attn2   = (bf16_t*)alloc(2ULL * BATCH * HEADS * SEQ * NP);
    bf16_t* aout    = (bf16_t*)alloc(2ULL * TOK * DIM);

    dim3 B256(256);
    const int NM = (TOK + 127) / 128;   // 50
    concat_k<<<(TOK * DIM) / 256, B256, 0, stream>>>(x, cls, xbuf);
    tcvt_k<<<dim3((FEAT + 31) / 32, DIM / 32), B256, 0, stream>>>(w_head, wt_head, DIM, FEAT);

    for (int l = 0; l < DEPTH; l++) {
        ln_k<<<TOK, B256, 0, stream>>>(xbuf, DIM, ln1_g + l * DIM, ln1_b + l * DIM, h_ln);
        tcvt_k<<<dim3(2304 / 32, DIM / 32), B256, 0, stream>>>(w_qkv + (long)l * DIM * 2304, wt, DIM, 2304);
        gemm_k<0><<<NM * 18, B256, 0, stream>>>(h_ln, wt, nullptr, nullptr, qkv, TOK, 2304, DIM, 18);
        qk_k<<<dim3(4, 4, BATCH * HEADS), B256, 0, stream>>>(qkv, dots);
        smre_k<<<TOK, B256, 0, stream>>>(
            dots, reattn_w + l * HEADS * HEADS, reattn_g + l * HEADS, reattn_b + l * HEADS, attn2);
        pv_k<<<dim3(4, BATCH * HEADS), B256, 0, stream>>>(attn2, qkv, aout);
        tcvt_k<<<dim3(DIM / 32, DIM / 32), B256, 0, stream>>>(w_out + (long)l * DIM * DIM, wt, DIM, DIM);
        gemm_k<1><<<NM * 6, B256, 0, stream>>>(aout, wt, b_out + l * DIM, xbuf, nullptr, TOK, DIM, DIM, 6);
        ln_k<<<TOK, B256, 0, stream>>>(xbuf, DIM, ln2_g + l * DIM, ln2_b + l * DIM, h_ln);
        tcvt_k<<<dim3(MLPD / 32, DIM / 32), B256, 0, stream>>>(w1 + (long)l * DIM * MLPD, wt, DIM, MLPD);
        gemm_k<2><<<NM * 24, B256, 0, stream>>>(h_ln, wt, b1 + l * MLPD, nullptr, h_mid, TOK, MLPD, DIM, 24);
        tcvt_k<<<dim3(DIM / 32, MLPD / 32), B256, 0, stream>>>(w2 + (long)l * MLPD * DIM, wt, MLPD, DIM);
        gemm_k<1><<<NM * 6, B256, 0, stream>>>(h_mid, wt, b2 + l * DIM, xbuf, nullptr, TOK, DIM, MLPD, 6);
    }

    ln_k<<<BATCH, B256, 0, stream>>>(xbuf, (long)SEQ * DIM, lnf_g, lnf_b, h_ln);
    gemm_h<<<dim3(1, 8), B256, 0, stream>>>(h_ln, wt_head, b_head, out, BATCH, FEAT, DIM);
}